// Round 1
// 33.026 us; speedup vs baseline: 1.3243x; 1.3243x over previous
//
#include <hip/hip_runtime.h>
#include <hip/hip_bf16.h>

typedef __bf16  bf16x8 __attribute__((ext_vector_type(8)));
typedef float   f32x4  __attribute__((ext_vector_type(4)));

constexpr int   Bsz   = 4096;   // anchors
constexpr int   D     = 512;    // embedding dim
constexpr int   Pn    = 2;      // positives per anchor
constexpr float INV_T = 1.0f / 0.07f;
constexpr float EPSF  = 1e-8f;

constexpr int NT = 528;          // triangular 128x128 tiles: 32*33/2
constexpr int POS_BLOCKS = Bsz / 4;  // 1024: one anchor per wave, 4 waves/block

#define GLOBAL_AS __attribute__((address_space(1)))
#define LDS_AS    __attribute__((address_space(3)))

// global -> LDS direct copy, 16 B per lane; LDS dest = wave-uniform base + lane*16
__device__ __forceinline__ void stage16(const void* g, void* l) {
  __builtin_amdgcn_global_load_lds((const GLOBAL_AS unsigned int*)g,
                                   (LDS_AS unsigned int*)l, 16, 0, 0);
}

// ---------------------------------------------------------------------------
// Kernel 1: L2-normalize anchors -> bf16; zero neg accumulator and out.
// 1024 blocks x 256 threads, one anchor row per wave.
// ---------------------------------------------------------------------------
__global__ __launch_bounds__(256) void norm_kernel(
    const float* __restrict__ A, __hip_bfloat16* __restrict__ Abf,
    float* __restrict__ neg, float* __restrict__ out) {
  const int lane = threadIdx.x & 63;
  const int wave = threadIdx.x >> 6;
  const int row  = blockIdx.x * 4 + wave;
  const int gid  = blockIdx.x * 256 + threadIdx.x;
  if (gid < Bsz) neg[gid] = 0.0f;   // fresh accumulator every launch
  if (gid == 0)  out[0]   = 0.0f;   // loss accumulator

  const float4* ap = reinterpret_cast<const float4*>(A + (size_t)row * D + lane * 8);
  const float4 v0 = ap[0];
  const float4 v1 = ap[1];
  float ss = v0.x*v0.x + v0.y*v0.y + v0.z*v0.z + v0.w*v0.w
           + v1.x*v1.x + v1.y*v1.y + v1.z*v1.z + v1.w*v1.w;
#pragma unroll
  for (int m = 1; m < 64; m <<= 1) ss += __shfl_xor(ss, m);
  const float inv = rsqrtf(ss);

  union { __hip_bfloat16 h[8]; uint4 u; } o;
  o.h[0] = __float2bfloat16(v0.x * inv);
  o.h[1] = __float2bfloat16(v0.y * inv);
  o.h[2] = __float2bfloat16(v0.z * inv);
  o.h[3] = __float2bfloat16(v0.w * inv);
  o.h[4] = __float2bfloat16(v1.x * inv);
  o.h[5] = __float2bfloat16(v1.y * inv);
  o.h[6] = __float2bfloat16(v1.z * inv);
  o.h[7] = __float2bfloat16(v1.w * inv);
  reinterpret_cast<uint4*>(Abf + (size_t)row * D + lane * 8)[0] = o.u;
}

// ---------------------------------------------------------------------------
// Kernel 2 (fused): blocks [0, NT): symmetric neg-sum GEMM (verified
// 128x128/BK=32/16x16x32 structure with conflict-free XOR-swizzled staging).
// Blocks [NT, NT+POS_BLOCKS): fp32-exact pos dot-products (one anchor per
// wave, both positives) — HBM-bound, backfills the CUs while the GEMM runs.
// ---------------------------------------------------------------------------
#define BK 32

__global__ __launch_bounds__(256) void negsum_pos_kernel(
    const __hip_bfloat16* __restrict__ Abf, float* __restrict__ neg,
    const float* __restrict__ A, const float* __restrict__ Pm,
    float* __restrict__ pos) {
  const int tid  = threadIdx.x;
  const int lane = tid & 63;
  const int wave = tid >> 6;

  if (blockIdx.x >= NT) {
    // ---- pos role: anchor b, positives 2b and 2b+1, all fp32 exact ----
    const int b = (blockIdx.x - NT) * 4 + wave;     // 0..4095

    const float4* ap  = reinterpret_cast<const float4*>(A  + (size_t)b * D + lane * 8);
    const float4* p0p = reinterpret_cast<const float4*>(Pm + (size_t)(2 * b) * D + lane * 8);
    const float4* p1p = reinterpret_cast<const float4*>(Pm + (size_t)(2 * b + 1) * D + lane * 8);
    const float4 a0 = ap[0],  a1 = ap[1];
    const float4 q0 = p0p[0], q1 = p0p[1];
    const float4 r0 = p1p[0], r1 = p1p[1];

    float daa  = a0.x*a0.x + a0.y*a0.y + a0.z*a0.z + a0.w*a0.w
               + a1.x*a1.x + a1.y*a1.y + a1.z*a1.z + a1.w*a1.w;
    float dpp0 = q0.x*q0.x + q0.y*q0.y + q0.z*q0.z + q0.w*q0.w
               + q1.x*q1.x + q1.y*q1.y + q1.z*q1.z + q1.w*q1.w;
    float dpp1 = r0.x*r0.x + r0.y*r0.y + r0.z*r0.z + r0.w*r0.w
               + r1.x*r1.x + r1.y*r1.y + r1.z*r1.z + r1.w*r1.w;
    float dap0 = a0.x*q0.x + a0.y*q0.y + a0.z*q0.z + a0.w*q0.w
               + a1.x*q1.x + a1.y*q1.y + a1.z*q1.z + a1.w*q1.w;
    float dap1 = a0.x*r0.x + a0.y*r0.y + a0.z*r0.z + a0.w*r0.w
               + a1.x*r1.x + a1.y*r1.y + a1.z*r1.z + a1.w*r1.w;
#pragma unroll
    for (int m = 1; m < 64; m <<= 1) {
      daa  += __shfl_xor(daa,  m);
      dpp0 += __shfl_xor(dpp0, m);
      dpp1 += __shfl_xor(dpp1, m);
      dap0 += __shfl_xor(dap0, m);
      dap1 += __shfl_xor(dap1, m);
    }
    if (lane == 0) {
      const float ia = rsqrtf(daa);
      pos[2 * b]     = dap0 * ia * rsqrtf(dpp0) * INV_T;
      pos[2 * b + 1] = dap1 * ia * rsqrtf(dpp1) * INV_T;
    }
    return;
  }

  // ---- negsum role: triangular tile GEMM ----
  __shared__ __attribute__((aligned(16))) ushort At[128 * BK];
  __shared__ __attribute__((aligned(16))) ushort Bt[128 * BK];

  // triangular decode: 0 <= bx <= by <= 31
  const int i = blockIdx.x;
  int by = (int)((sqrtf(8.0f * (float)i + 1.0f) - 1.0f) * 0.5f);
  while ((by + 1) * (by + 2) / 2 <= i) ++by;
  while (by * (by + 1) / 2 > i) --by;
  const int bx = i - by * (by + 1) / 2;

  const int brow = bx * 128;
  const int bcol = by * 128;
  const bool offdiag = (bx != by);

  const int waveM = wave >> 1;        // 0..1
  const int waveN = wave & 1;         // 0..1

  const int fr  = lane & 15;          // row-in-fragment
  const int kch = lane >> 4;          // k-chunk 0..3
  const int ckr = (kch ^ ((fr >> 1) & 3)) * 8;  // swizzled read chunk (ushorts)

  // staging source indices for this lane
  const int srow = lane >> 2;                        // 0..15 within a 16-row call
  const int sck  = ((lane & 3) ^ ((lane >> 3) & 3)); // swizzled source chunk

  f32x4 acc[4][4] = {};

  for (int k0 = 0; k0 < D; k0 += BK) {
    // ---- stage via global_load_lds: wave w covers rows [w*32, w*32+32) ----
#pragma unroll
    for (int t = 0; t < 2; ++t) {
      const int r0 = wave * 32 + t * 16;
      stage16(&Abf[(size_t)(brow + r0 + srow) * D + k0 + sck * 8], &At[r0 * BK]);
      stage16(&Abf[(size_t)(bcol + r0 + srow) * D + k0 + sck * 8], &Bt[r0 * BK]);
    }
    __syncthreads();

    // ---- fragments: swizzled ds_read_b128 ----
    bf16x8 af[4], bfv[4];
#pragma unroll
    for (int m = 0; m < 4; ++m)
      af[m] = *reinterpret_cast<const bf16x8*>(
          &At[(waveM * 64 + m * 16 + fr) * BK + ckr]);
#pragma unroll
    for (int n = 0; n < 4; ++n)
      bfv[n] = *reinterpret_cast<const bf16x8*>(
          &Bt[(waveN * 64 + n * 16 + fr) * BK + ckr]);

#pragma unroll
    for (int m = 0; m < 4; ++m)
#pragma unroll
      for (int n = 0; n < 4; ++n)
        acc[m][n] = __builtin_amdgcn_mfma_f32_16x16x32_bf16(
            af[m], bfv[n], acc[m][n], 0, 0, 0);
    __syncthreads();
  }

  // ---- epilogue: exp (skip diagonal), row sums + (off-diag) col sums ----
  const int q = lane >> 4;            // C/D: row = q*4 + r, col = lane&15
  float colsum[4] = {0.f, 0.f, 0.f, 0.f};
#pragma unroll
  for (int m = 0; m < 4; ++m) {
#pragma unroll
    for (int r = 0; r < 4; ++r) {
      const int grow = brow + waveM * 64 + m * 16 + q * 4 + r;
      float rs = 0.0f;
#pragma unroll
      for (int n = 0; n < 4; ++n) {
        const int gcol = bcol + waveN * 64 + n * 16 + fr;
        const float e = (grow != gcol) ? __expf(acc[m][n][r] * INV_T) : 0.0f;
        rs += e;
        colsum[n] += e;
      }
      rs += __shfl_xor(rs, 1);
      rs += __shfl_xor(rs, 2);
      rs += __shfl_xor(rs, 4);
      rs += __shfl_xor(rs, 8);
      if (fr == 0) atomicAdd(&neg[grow], rs);
    }
  }
  if (offdiag) {
#pragma unroll
    for (int n = 0; n < 4; ++n) {
      float cs = colsum[n];
      cs += __shfl_xor(cs, 16);   // combine q-groups (rows q*4..q*4+3)
      cs += __shfl_xor(cs, 32);
      if (q == 0) atomicAdd(&neg[bcol + waveN * 64 + n * 16 + fr], cs);
    }
  }
}

// ---------------------------------------------------------------------------
// Kernel 3: parallel loss mean: loss = log(exp(pos) + neg_b + eps) - pos
// 32 blocks x 256 threads = exactly 8192 elements, one per thread.
// ---------------------------------------------------------------------------
__global__ __launch_bounds__(256) void loss_kernel(
    const float* __restrict__ pos, const float* __restrict__ neg,
    float* __restrict__ out) {
  const int i = blockIdx.x * 256 + threadIdx.x;
  const int b = i >> 1;               // Pn = 2
  const float po = pos[i];
  float s = logf(expf(po) + neg[b] + EPSF) - po;
#pragma unroll
  for (int m = 1; m < 64; m <<= 1) s += __shfl_xor(s, m);
  __shared__ float wsum[4];
  if ((threadIdx.x & 63) == 0) wsum[threadIdx.x >> 6] = s;
  __syncthreads();
  if (threadIdx.x == 0)
    atomicAdd(out, (wsum[0] + wsum[1] + wsum[2] + wsum[3]) * (1.0f / (Bsz * Pn)));
}

// ---------------------------------------------------------------------------
extern "C" void kernel_launch(void* const* d_in, const int* in_sizes, int n_in,
                              void* d_out, int out_size, void* d_ws, size_t ws_size,
                              hipStream_t stream) {
  const float* A  = (const float*)d_in[0];   // 4096 x 512
  const float* Pm = (const float*)d_in[1];   // 8192 x 512
  float* out = (float*)d_out;

  // workspace layout
  __hip_bfloat16* Abf = (__hip_bfloat16*)d_ws;                       // 4 MiB
  float* pos = (float*)((char*)d_ws + (size_t)Bsz * D * 2);          // 32 KiB
  float* neg = pos + Bsz * Pn;                                       // 16 KiB

  norm_kernel<<<Bsz / 4, 256, 0, stream>>>(A, Abf, neg, out);
  negsum_pos_kernel<<<NT + POS_BLOCKS, 256, 0, stream>>>(Abf, neg, A, Pm, pos);
  loss_kernel<<<32, 256, 0, stream>>>(pos, neg, out);
}